// Round 6
// baseline (427.132 us; speedup 1.0000x reference)
//
#include <hip/hip_runtime.h>

#define FEAT 83
#define DIMF 64
#define LAT  32
#define THREADS 256
#define RPB  128            // rows per block: 4 waves x 32 rows

typedef __attribute__((ext_vector_type(8))) short bf16x8;
typedef __attribute__((ext_vector_type(4))) float f32x4;

// LDS strides in bf16 elements (all rows 16B-aligned, <=2-way bank aliasing)
#define BT1_S 104           // W1^T  [64][104], K padded to 96, pad zeroed
#define BT2_S 72            // Wh0^T [32][72],  K=64
#define BT3_S 40            // Wh1^T [32][40],  K=32
#define HT_S  72            // per-wave h tile [32][72]
#define GT_S  40            // per-wave g tile [32][40]
#define XT_S  85            // x-tile row stride in dwords (odd -> 2-way banks)

// region map (shorts):
//  phase0: x-tile fp32 [128][85] = dwords 0..10880 = shorts 0..21760
//  phase1: bt1 hi/lo at 0..13312 (A region), bt2 hi/lo at 18432..23040 (B)
//  phase2: per-wave scratch wv*4608 in A region (ht then gt overlay)
#define A_OFF   0
#define BT1LO   6656
#define WSCR    4608        // per-wave scratch shorts
#define B_OFF   18432       // bt2_hi
#define BT2LO   (B_OFF + 2304)
#define C_OFF   23040       // bt3_hi (never overlaps x-tile: 23040 > 21760)
#define BT3LO   (C_OFF + 1280)
#define M_OFF   25600       // 128 floats of row-mask (byte 51200, 16B aligned)
#define SM_TOT  25856       // 51712 bytes -> 3 blocks/CU

__device__ __forceinline__ short f2b(float f) {   // fp32 -> bf16 RNE
    unsigned u = __float_as_uint(f);
    u += 0x7fffu + ((u >> 16) & 1u);
    return (short)(u >> 16);
}
__device__ __forceinline__ float b2f(short h) {   // bf16 -> fp32 exact
    return __uint_as_float(((unsigned)(unsigned short)h) << 16);
}

__global__ __launch_bounds__(THREADS, 3)
void material_encoder_kernel(const float* __restrict__ inp,
                             const float* __restrict__ shiftp,
                             const float* __restrict__ W1,
                             const float* __restrict__ b1,
                             const float* __restrict__ Wh0,
                             const float* __restrict__ bh0,
                             const float* __restrict__ Wh1,
                             const float* __restrict__ bh1,
                             float* __restrict__ out,
                             int nrows)
{
    __shared__ __align__(16) short sm[SM_TOT];
    float* maskf = (float*)(sm + M_OFF);
    float* xt    = (float*)sm;          // phase-0 overlay: [128][85] fp32

    const int t    = threadIdx.x;
    const int lane = t & 63;
    const int wv   = t >> 6;
    const int lr   = lane & 15;        // A-row / B-col / C-col index
    const int lq   = (lane >> 4) & 3;  // lane quarter

    // ---- phase 0: coalesced stage of the 128x83 x-tile into LDS ----
    {
        const float4* __restrict__ src4 =
            (const float4*)(inp + (long long)blockIdx.x * (RPB * FEAT));
        #pragma unroll
        for (int it = 0; it < 11; ++it) {
            const int idx = it * THREADS + t;          // float4 index, < 2656
            if (idx < (RPB * FEAT / 4)) {
                const float4 v = src4[idx];
                const int d0 = idx * 4;
                int r, c;
                r = (d0 + 0) / FEAT; c = (d0 + 0) - r * FEAT; xt[r * XT_S + c] = v.x;
                r = (d0 + 1) / FEAT; c = (d0 + 1) - r * FEAT; xt[r * XT_S + c] = v.y;
                r = (d0 + 2) / FEAT; c = (d0 + 2) - r * FEAT; xt[r * XT_S + c] = v.z;
                r = (d0 + 3) / FEAT; c = (d0 + 3) - r * FEAT; xt[r * XT_S + c] = v.w;
            }
        }
    }

    // biases per lane (L1/L2 cached), while staging settles
    float bias1[4], bias2[2], bias3[2];
    #pragma unroll
    for (int n = 0; n < 4; ++n) bias1[n] = b1[lr + 16 * n];
    #pragma unroll
    for (int n = 0; n < 2; ++n) { bias2[n] = bh0[lr + 16 * n]; bias3[n] = bh1[lr + 16 * n]; }
    const float sh = shiftp[0];
    const int Rw = blockIdx.x * RPB + wv * 32;

    __syncthreads();   // x-tile staged

    // ---- A fragments (x+shift) hi/lo from LDS; nz mask on raw x ----
    // frag layout (16x16x32): row = lr, k = 8*lq + i (+32*s)
    // k >= 83 clamps to 82: duplicate finite value x zeroed B-pad -> 0
    bf16x8 a1h[2][3], a1l[2][3];
    float nzm[2];
    #pragma unroll
    for (int m = 0; m < 2; ++m) {
        const float* __restrict__ xr = xt + (wv * 32 + 16 * m + lr) * XT_S;
        float nz = 0.f;
        #pragma unroll
        for (int s = 0; s < 3; ++s) {
            const int k0 = 32 * s + 8 * lq;
            bf16x8 fh, fl;
            #pragma unroll
            for (int i = 0; i < 8; ++i) {
                int kk = k0 + i;
                kk = (kk < FEAT) ? kk : (FEAT - 1);
                const float x = xr[kk];
                nz = fmaxf(nz, fabsf(x));
                const float xs = x + sh;
                const short hi = f2b(xs);
                fh[i] = hi;
                fl[i] = f2b(xs - b2f(hi));
            }
            a1h[m][s] = fh;
            a1l[m][s] = fl;
        }
        nzm[m] = nz;
    }
    #pragma unroll
    for (int m = 0; m < 2; ++m) {     // full-row max across the 4 k-quarters
        nzm[m] = fmaxf(nzm[m], __shfl_xor(nzm[m], 16));
        nzm[m] = fmaxf(nzm[m], __shfl_xor(nzm[m], 32));
    }
    if (lq == 0) {
        maskf[wv * 32 + lr]      = nzm[0];
        maskf[wv * 32 + 16 + lr] = nzm[1];
    }

    __syncthreads();   // x-tile dead -> stage weights over it

    // ---- stage weights to LDS as bf16 hi/lo B^T tiles ----
    for (int f = t; f < FEAT * DIMF; f += THREADS) {      // W1: 83x64
        int j = f >> 6, c = f & 63;
        float w = W1[f];
        short hi = f2b(w);
        sm[A_OFF + c * BT1_S + j] = hi;
        sm[BT1LO + c * BT1_S + j] = f2b(w - b2f(hi));
    }
    if (t < DIMF) {                                       // zero K-pad 83..95
        #pragma unroll
        for (int k = FEAT; k < 96; ++k) {
            sm[A_OFF + t * BT1_S + k] = 0;
            sm[BT1LO + t * BT1_S + k] = 0;
        }
    }
    for (int f = t; f < DIMF * LAT; f += THREADS) {       // Wh0: 64x32
        int j = f >> 5, c = f & 31;
        float w = Wh0[f];
        short hi = f2b(w);
        sm[B_OFF + c * BT2_S + j] = hi;
        sm[BT2LO + c * BT2_S + j] = f2b(w - b2f(hi));
    }
    for (int f = t; f < LAT * LAT; f += THREADS) {        // Wh1: 32x32
        int j = f >> 5, c = f & 31;
        float w = Wh1[f];
        short hi = f2b(w);
        sm[C_OFF + c * BT3_S + j] = hi;
        sm[BT3LO + c * BT3_S + j] = f2b(w - b2f(hi));
    }

    __syncthreads();   // weights staged

    // ---- layer 1: 2(M) x 4(N) x 3(K) x 3 split-terms ----
    f32x4 acc[2][4];
    #pragma unroll
    for (int m = 0; m < 2; ++m)
        #pragma unroll
        for (int n = 0; n < 4; ++n)
            acc[m][n] = (f32x4){bias1[n], bias1[n], bias1[n], bias1[n]};

    #pragma unroll
    for (int s = 0; s < 3; ++s)
        #pragma unroll
        for (int n = 0; n < 4; ++n) {
            bf16x8 bh = *(const bf16x8*)&sm[A_OFF + (lr + 16 * n) * BT1_S + 32 * s + 8 * lq];
            bf16x8 bl = *(const bf16x8*)&sm[BT1LO + (lr + 16 * n) * BT1_S + 32 * s + 8 * lq];
            #pragma unroll
            for (int m = 0; m < 2; ++m) {
                acc[m][n] = __builtin_amdgcn_mfma_f32_16x16x32_bf16(a1h[m][s], bh, acc[m][n], 0, 0, 0);
                acc[m][n] = __builtin_amdgcn_mfma_f32_16x16x32_bf16(a1l[m][s], bh, acc[m][n], 0, 0, 0);
                acc[m][n] = __builtin_amdgcn_mfma_f32_16x16x32_bf16(a1h[m][s], bl, acc[m][n], 0, 0, 0);
            }
        }

    __syncthreads();   // all waves done reading bt1 -> region A = per-wave scratch

    // ---- h: relu -> hi/lo bf16 -> per-wave LDS transpose (C-layout -> A-layout) ----
    short* ht_hi = sm + A_OFF + wv * WSCR;
    short* ht_lo = ht_hi + 2304;
    #pragma unroll
    for (int m = 0; m < 2; ++m)
        #pragma unroll
        for (int n = 0; n < 4; ++n)
            #pragma unroll
            for (int r = 0; r < 4; ++r) {
                float hv = fmaxf(acc[m][n][r], 0.f);
                short hi = f2b(hv);
                const int idx = (16 * m + 4 * lq + r) * HT_S + lr + 16 * n;
                ht_hi[idx] = hi;
                ht_lo[idx] = f2b(hv - b2f(hi));
            }

    // ---- layer 2: 2 x 2 x 2 x 3 terms (same-wave ds_write->ds_read, no barrier) ----
    f32x4 acc2[2][2];
    #pragma unroll
    for (int m = 0; m < 2; ++m)
        #pragma unroll
        for (int n = 0; n < 2; ++n)
            acc2[m][n] = (f32x4){bias2[n], bias2[n], bias2[n], bias2[n]};

    #pragma unroll
    for (int s = 0; s < 2; ++s) {
        bf16x8 a2h[2], a2l[2];
        #pragma unroll
        for (int m = 0; m < 2; ++m) {
            const int idx = (lr + 16 * m) * HT_S + 32 * s + 8 * lq;
            a2h[m] = *(const bf16x8*)&ht_hi[idx];
            a2l[m] = *(const bf16x8*)&ht_lo[idx];
        }
        #pragma unroll
        for (int n = 0; n < 2; ++n) {
            bf16x8 bh = *(const bf16x8*)&sm[B_OFF + (lr + 16 * n) * BT2_S + 32 * s + 8 * lq];
            bf16x8 bl = *(const bf16x8*)&sm[BT2LO + (lr + 16 * n) * BT2_S + 32 * s + 8 * lq];
            #pragma unroll
            for (int m = 0; m < 2; ++m) {
                acc2[m][n] = __builtin_amdgcn_mfma_f32_16x16x32_bf16(a2h[m], bh, acc2[m][n], 0, 0, 0);
                acc2[m][n] = __builtin_amdgcn_mfma_f32_16x16x32_bf16(a2l[m], bh, acc2[m][n], 0, 0, 0);
                acc2[m][n] = __builtin_amdgcn_mfma_f32_16x16x32_bf16(a2h[m], bl, acc2[m][n], 0, 0, 0);
            }
        }
    }

    // ---- g: relu -> hi/lo -> overlay own (dead) ht scratch; same-wave order ----
    short* gt_hi = sm + A_OFF + wv * WSCR;
    short* gt_lo = gt_hi + 1280;
    #pragma unroll
    for (int m = 0; m < 2; ++m)
        #pragma unroll
        for (int n = 0; n < 2; ++n)
            #pragma unroll
            for (int r = 0; r < 4; ++r) {
                float gv = fmaxf(acc2[m][n][r], 0.f);
                short hi = f2b(gv);
                const int idx = (16 * m + 4 * lq + r) * GT_S + lr + 16 * n;
                gt_hi[idx] = hi;
                gt_lo[idx] = f2b(gv - b2f(hi));
            }

    // ---- layer 3: 2 x 2 x 1 x 3 terms ----
    f32x4 acc3[2][2];
    #pragma unroll
    for (int m = 0; m < 2; ++m)
        #pragma unroll
        for (int n = 0; n < 2; ++n)
            acc3[m][n] = (f32x4){bias3[n], bias3[n], bias3[n], bias3[n]};

    {
        bf16x8 a3h[2], a3l[2];
        #pragma unroll
        for (int m = 0; m < 2; ++m) {
            const int idx = (lr + 16 * m) * GT_S + 8 * lq;
            a3h[m] = *(const bf16x8*)&gt_hi[idx];
            a3l[m] = *(const bf16x8*)&gt_lo[idx];
        }
        #pragma unroll
        for (int n = 0; n < 2; ++n) {
            bf16x8 bh = *(const bf16x8*)&sm[C_OFF + (lr + 16 * n) * BT3_S + 8 * lq];
            bf16x8 bl = *(const bf16x8*)&sm[BT3LO + (lr + 16 * n) * BT3_S + 8 * lq];
            #pragma unroll
            for (int m = 0; m < 2; ++m) {
                acc3[m][n] = __builtin_amdgcn_mfma_f32_16x16x32_bf16(a3h[m], bh, acc3[m][n], 0, 0, 0);
                acc3[m][n] = __builtin_amdgcn_mfma_f32_16x16x32_bf16(a3l[m], bh, acc3[m][n], 0, 0, 0);
                acc3[m][n] = __builtin_amdgcn_mfma_f32_16x16x32_bf16(a3h[m], bl, acc3[m][n], 0, 0, 0);
            }
        }
    }

    // ---- relu + row L2 norm (reduce over cols = over lr lanes) + mask ----
    float er[2][2][4];
    float ssq[2][4];
    #pragma unroll
    for (int m = 0; m < 2; ++m)
        #pragma unroll
        for (int r = 0; r < 4; ++r) ssq[m][r] = 0.f;
    #pragma unroll
    for (int m = 0; m < 2; ++m)
        #pragma unroll
        for (int n = 0; n < 2; ++n)
            #pragma unroll
            for (int r = 0; r < 4; ++r) {
                float e = fmaxf(acc3[m][n][r], 0.f);
                er[m][n][r] = e;
                ssq[m][r] = fmaf(e, e, ssq[m][r]);
            }
    #pragma unroll
    for (int msk = 1; msk <= 8; msk <<= 1)
        #pragma unroll
        for (int m = 0; m < 2; ++m)
            #pragma unroll
            for (int r = 0; r < 4; ++r)
                ssq[m][r] += __shfl_xor(ssq[m][r], msk);

    const float* maskp = maskf + wv * 32;
    f32x4 mk[2];
    mk[0] = *(const f32x4*)&maskp[4 * lq];
    mk[1] = *(const f32x4*)&maskp[16 + 4 * lq];

    float sc[2][4];
    #pragma unroll
    for (int m = 0; m < 2; ++m)
        #pragma unroll
        for (int r = 0; r < 4; ++r)
            // rsqrt(max(ss,1e-24)) == 1/max(sqrt(ss),1e-12)
            sc[m][r] = (mk[m][r] != 0.f) ? rsqrtf(fmaxf(ssq[m][r], 1e-24f)) : 0.f;

    // ---- store 3 copies (quarter-wave 64B segments) ----
    const int osz = nrows * LAT;                 // 64M, fits int
    float* __restrict__ ob = out + (long long)Rw * LAT;
    #pragma unroll
    for (int m = 0; m < 2; ++m)
        #pragma unroll
        for (int r = 0; r < 4; ++r) {
            const int ro = (16 * m + 4 * lq + r) * LAT;
            #pragma unroll
            for (int n = 0; n < 2; ++n) {
                const float vv = er[m][n][r] * sc[m][r];
                const int cc = ro + lr + 16 * n;
                ob[cc]           = vv;
                ob[osz + cc]     = vv;
                ob[2 * osz + cc] = vv;
            }
        }
}

extern "C" void kernel_launch(void* const* d_in, const int* in_sizes, int n_in,
                              void* d_out, int out_size, void* d_ws, size_t ws_size,
                              hipStream_t stream) {
    const float* inp    = (const float*)d_in[0];
    const float* shiftp = (const float*)d_in[1];
    const float* W1     = (const float*)d_in[2];
    const float* b1     = (const float*)d_in[3];
    const float* Wh0    = (const float*)d_in[4];
    const float* bh0    = (const float*)d_in[5];
    const float* Wh1    = (const float*)d_in[6];
    const float* bh1    = (const float*)d_in[7];
    float* out = (float*)d_out;

    const int nrows = in_sizes[0] / FEAT;      // 2,000,000 = 128 * 15625
    const int blocks = nrows / RPB;            // exact

    material_encoder_kernel<<<dim3(blocks), dim3(THREADS), 0, stream>>>(
        inp, shiftp, W1, b1, Wh0, bh0, Wh1, bh1, out, nrows);
}

// Round 7
// 420.484 us; speedup vs baseline: 1.0158x; 1.0158x over previous
//
#include <hip/hip_runtime.h>

#define FEAT 83
#define DIMF 64
#define LAT  32
#define THREADS 256
#define RPB  128            // rows per block: 4 waves x 32 rows

typedef __attribute__((ext_vector_type(8))) short bf16x8;
typedef __attribute__((ext_vector_type(4))) float f32x4;

// LDS strides in bf16 elements (all rows 16B-aligned, <=2-way bank aliasing)
#define BT1_S 104           // W1^T  [64][104], K padded to 96, pad zeroed
#define BT2_S 72            // Wh0^T [32][72],  K=64
#define BT3_S 40            // Wh1^T [32][40],  K=32
#define HT_S  72            // per-wave h tile [32][72]
#define GT_S  40            // per-wave g tile [32][40]

// region map (shorts):
//  phase0: x-tile fp32 LINEAR [128*83] = dwords 0..10624 = shorts 0..21248
//          (same layout as global -> ds_write_b128 stride-1, conflict-free;
//           reads at row stride 83 dwords: bank=(19*lr+8*lq)%32 = exact 2-way)
//  phase1: bt1 hi/lo at 0..13312 (A region), bt2 hi/lo at 18432..23040 (B)
//          -- staged only AFTER x-frag reads complete (barrier), overlays x
//  phase2: per-wave scratch wv*4608 in A region (ht then gt overlay)
#define A_OFF   0
#define BT1LO   6656
#define WSCR    4608        // per-wave scratch shorts
#define B_OFF   18432       // bt2_hi
#define BT2LO   (B_OFF + 2304)
#define C_OFF   23040       // bt3_hi (23040 > 21248: never overlaps x-tile)
#define BT3LO   (C_OFF + 1280)
#define M_OFF   25600       // 128 floats of row-mask (byte 51200, 16B aligned)
#define SM_TOT  25856       // 51712 bytes -> 3 blocks/CU

__device__ __forceinline__ short f2b(float f) {   // fp32 -> bf16 RNE
    unsigned u = __float_as_uint(f);
    u += 0x7fffu + ((u >> 16) & 1u);
    return (short)(u >> 16);
}
__device__ __forceinline__ float b2f(short h) {   // bf16 -> fp32 exact
    return __uint_as_float(((unsigned)(unsigned short)h) << 16);
}

__global__ __launch_bounds__(THREADS, 3)
void material_encoder_kernel(const float* __restrict__ inp,
                             const float* __restrict__ shiftp,
                             const float* __restrict__ W1,
                             const float* __restrict__ b1,
                             const float* __restrict__ Wh0,
                             const float* __restrict__ bh0,
                             const float* __restrict__ Wh1,
                             const float* __restrict__ bh1,
                             float* __restrict__ out,
                             int nrows)
{
    __shared__ __align__(16) short sm[SM_TOT];
    float* maskf = (float*)(sm + M_OFF);
    float* xt    = (float*)sm;          // phase-0 overlay: linear [128*83] fp32

    const int t    = threadIdx.x;
    const int lane = t & 63;
    const int wv   = t >> 6;
    const int lr   = lane & 15;        // A-row / B-col / C-col index
    const int lq   = (lane >> 4) & 3;  // lane quarter

    // ---- phase 0: coalesced stage of the 128x83 x-tile, LINEAR layout ----
    {
        const float4* __restrict__ src4 =
            (const float4*)(inp + (long long)blockIdx.x * (RPB * FEAT));
        float4* dst4 = (float4*)xt;
        #pragma unroll
        for (int it = 0; it < 11; ++it) {
            const int idx = it * THREADS + t;          // float4 index
            if (idx < (RPB * FEAT / 4))                // 2656
                dst4[idx] = src4[idx];                 // ds_write_b128, stride-1
        }
    }

    // biases per lane (L1/L2 cached), while staging settles
    float bias1[4], bias2[2], bias3[2];
    #pragma unroll
    for (int n = 0; n < 4; ++n) bias1[n] = b1[lr + 16 * n];
    #pragma unroll
    for (int n = 0; n < 2; ++n) { bias2[n] = bh0[lr + 16 * n]; bias3[n] = bh1[lr + 16 * n]; }
    const float sh = shiftp[0];
    const int Rw = blockIdx.x * RPB + wv * 32;

    __syncthreads();   // x-tile staged

    // ---- A fragments (x+shift) hi/lo from LDS; nz mask on raw x ----
    // frag layout (16x16x32): row = lr, k = 8*lq + i (+32*s)
    // k >= 83 clamps to 82: duplicate finite value x zeroed B-pad -> 0
    bf16x8 a1h[2][3], a1l[2][3];
    float nzm[2];
    #pragma unroll
    for (int m = 0; m < 2; ++m) {
        const float* __restrict__ xr = xt + (wv * 32 + 16 * m + lr) * FEAT;
        float nz = 0.f;
        #pragma unroll
        for (int s = 0; s < 3; ++s) {
            const int k0 = 32 * s + 8 * lq;
            bf16x8 fh, fl;
            #pragma unroll
            for (int i = 0; i < 8; ++i) {
                int kk = k0 + i;
                kk = (kk < FEAT) ? kk : (FEAT - 1);
                const float x = xr[kk];
                nz = fmaxf(nz, fabsf(x));
                const float xs = x + sh;
                const short hi = f2b(xs);
                fh[i] = hi;
                fl[i] = f2b(xs - b2f(hi));
            }
            a1h[m][s] = fh;
            a1l[m][s] = fl;
        }
        nzm[m] = nz;
    }
    #pragma unroll
    for (int m = 0; m < 2; ++m) {     // full-row max across the 4 k-quarters
        nzm[m] = fmaxf(nzm[m], __shfl_xor(nzm[m], 16));
        nzm[m] = fmaxf(nzm[m], __shfl_xor(nzm[m], 32));
    }
    if (lq == 0) {
        maskf[wv * 32 + lr]      = nzm[0];
        maskf[wv * 32 + 16 + lr] = nzm[1];
    }

    __syncthreads();   // x-tile dead -> stage weights over it

    // ---- stage weights to LDS as bf16 hi/lo B^T tiles ----
    for (int f = t; f < FEAT * DIMF; f += THREADS) {      // W1: 83x64
        int j = f >> 6, c = f & 63;
        float w = W1[f];
        short hi = f2b(w);
        sm[A_OFF + c * BT1_S + j] = hi;
        sm[BT1LO + c * BT1_S + j] = f2b(w - b2f(hi));
    }
    if (t < DIMF) {                                       // zero K-pad 83..95
        #pragma unroll
        for (int k = FEAT; k < 96; ++k) {
            sm[A_OFF + t * BT1_S + k] = 0;
            sm[BT1LO + t * BT1_S + k] = 0;
        }
    }
    for (int f = t; f < DIMF * LAT; f += THREADS) {       // Wh0: 64x32
        int j = f >> 5, c = f & 31;
        float w = Wh0[f];
        short hi = f2b(w);
        sm[B_OFF + c * BT2_S + j] = hi;
        sm[BT2LO + c * BT2_S + j] = f2b(w - b2f(hi));
    }
    for (int f = t; f < LAT * LAT; f += THREADS) {        // Wh1: 32x32
        int j = f >> 5, c = f & 31;
        float w = Wh1[f];
        short hi = f2b(w);
        sm[C_OFF + c * BT3_S + j] = hi;
        sm[BT3LO + c * BT3_S + j] = f2b(w - b2f(hi));
    }

    __syncthreads();   // weights staged

    // ---- layer 1: 2(M) x 4(N) x 3(K) x 3 split-terms ----
    f32x4 acc[2][4];
    #pragma unroll
    for (int m = 0; m < 2; ++m)
        #pragma unroll
        for (int n = 0; n < 4; ++n)
            acc[m][n] = (f32x4){bias1[n], bias1[n], bias1[n], bias1[n]};

    #pragma unroll
    for (int s = 0; s < 3; ++s)
        #pragma unroll
        for (int n = 0; n < 4; ++n) {
            bf16x8 bh = *(const bf16x8*)&sm[A_OFF + (lr + 16 * n) * BT1_S + 32 * s + 8 * lq];
            bf16x8 bl = *(const bf16x8*)&sm[BT1LO + (lr + 16 * n) * BT1_S + 32 * s + 8 * lq];
            #pragma unroll
            for (int m = 0; m < 2; ++m) {
                acc[m][n] = __builtin_amdgcn_mfma_f32_16x16x32_bf16(a1h[m][s], bh, acc[m][n], 0, 0, 0);
                acc[m][n] = __builtin_amdgcn_mfma_f32_16x16x32_bf16(a1l[m][s], bh, acc[m][n], 0, 0, 0);
                acc[m][n] = __builtin_amdgcn_mfma_f32_16x16x32_bf16(a1h[m][s], bl, acc[m][n], 0, 0, 0);
            }
        }

    __syncthreads();   // all waves done reading bt1 -> region A = per-wave scratch

    // ---- h: relu -> hi/lo bf16 -> per-wave LDS transpose (C-layout -> A-layout) ----
    short* ht_hi = sm + A_OFF + wv * WSCR;
    short* ht_lo = ht_hi + 2304;
    #pragma unroll
    for (int m = 0; m < 2; ++m)
        #pragma unroll
        for (int n = 0; n < 4; ++n)
            #pragma unroll
            for (int r = 0; r < 4; ++r) {
                float hv = fmaxf(acc[m][n][r], 0.f);
                short hi = f2b(hv);
                const int idx = (16 * m + 4 * lq + r) * HT_S + lr + 16 * n;
                ht_hi[idx] = hi;
                ht_lo[idx] = f2b(hv - b2f(hi));
            }

    // ---- layer 2: 2 x 2 x 2 x 3 terms (same-wave ds_write->ds_read, no barrier) ----
    f32x4 acc2[2][2];
    #pragma unroll
    for (int m = 0; m < 2; ++m)
        #pragma unroll
        for (int n = 0; n < 2; ++n)
            acc2[m][n] = (f32x4){bias2[n], bias2[n], bias2[n], bias2[n]};

    #pragma unroll
    for (int s = 0; s < 2; ++s) {
        bf16x8 a2h[2], a2l[2];
        #pragma unroll
        for (int m = 0; m < 2; ++m) {
            const int idx = (lr + 16 * m) * HT_S + 32 * s + 8 * lq;
            a2h[m] = *(const bf16x8*)&ht_hi[idx];
            a2l[m] = *(const bf16x8*)&ht_lo[idx];
        }
        #pragma unroll
        for (int n = 0; n < 2; ++n) {
            bf16x8 bh = *(const bf16x8*)&sm[B_OFF + (lr + 16 * n) * BT2_S + 32 * s + 8 * lq];
            bf16x8 bl = *(const bf16x8*)&sm[BT2LO + (lr + 16 * n) * BT2_S + 32 * s + 8 * lq];
            #pragma unroll
            for (int m = 0; m < 2; ++m) {
                acc2[m][n] = __builtin_amdgcn_mfma_f32_16x16x32_bf16(a2h[m], bh, acc2[m][n], 0, 0, 0);
                acc2[m][n] = __builtin_amdgcn_mfma_f32_16x16x32_bf16(a2l[m], bh, acc2[m][n], 0, 0, 0);
                acc2[m][n] = __builtin_amdgcn_mfma_f32_16x16x32_bf16(a2h[m], bl, acc2[m][n], 0, 0, 0);
            }
        }
    }

    // ---- g: relu -> hi/lo -> overlay own (dead) ht scratch; same-wave order ----
    short* gt_hi = sm + A_OFF + wv * WSCR;
    short* gt_lo = gt_hi + 1280;
    #pragma unroll
    for (int m = 0; m < 2; ++m)
        #pragma unroll
        for (int n = 0; n < 2; ++n)
            #pragma unroll
            for (int r = 0; r < 4; ++r) {
                float gv = fmaxf(acc2[m][n][r], 0.f);
                short hi = f2b(gv);
                const int idx = (16 * m + 4 * lq + r) * GT_S + lr + 16 * n;
                gt_hi[idx] = hi;
                gt_lo[idx] = f2b(gv - b2f(hi));
            }

    // ---- layer 3: 2 x 2 x 1 x 3 terms ----
    f32x4 acc3[2][2];
    #pragma unroll
    for (int m = 0; m < 2; ++m)
        #pragma unroll
        for (int n = 0; n < 2; ++n)
            acc3[m][n] = (f32x4){bias3[n], bias3[n], bias3[n], bias3[n]};

    {
        bf16x8 a3h[2], a3l[2];
        #pragma unroll
        for (int m = 0; m < 2; ++m) {
            const int idx = (lr + 16 * m) * GT_S + 8 * lq;
            a3h[m] = *(const bf16x8*)&gt_hi[idx];
            a3l[m] = *(const bf16x8*)&gt_lo[idx];
        }
        #pragma unroll
        for (int n = 0; n < 2; ++n) {
            bf16x8 bh = *(const bf16x8*)&sm[C_OFF + (lr + 16 * n) * BT3_S + 8 * lq];
            bf16x8 bl = *(const bf16x8*)&sm[BT3LO + (lr + 16 * n) * BT3_S + 8 * lq];
            #pragma unroll
            for (int m = 0; m < 2; ++m) {
                acc3[m][n] = __builtin_amdgcn_mfma_f32_16x16x32_bf16(a3h[m], bh, acc3[m][n], 0, 0, 0);
                acc3[m][n] = __builtin_amdgcn_mfma_f32_16x16x32_bf16(a3l[m], bh, acc3[m][n], 0, 0, 0);
                acc3[m][n] = __builtin_amdgcn_mfma_f32_16x16x32_bf16(a3h[m], bl, acc3[m][n], 0, 0, 0);
            }
        }
    }

    // ---- relu + row L2 norm (reduce over cols = over lr lanes) + mask ----
    float er[2][2][4];
    float ssq[2][4];
    #pragma unroll
    for (int m = 0; m < 2; ++m)
        #pragma unroll
        for (int r = 0; r < 4; ++r) ssq[m][r] = 0.f;
    #pragma unroll
    for (int m = 0; m < 2; ++m)
        #pragma unroll
        for (int n = 0; n < 2; ++n)
            #pragma unroll
            for (int r = 0; r < 4; ++r) {
                float e = fmaxf(acc3[m][n][r], 0.f);
                er[m][n][r] = e;
                ssq[m][r] = fmaf(e, e, ssq[m][r]);
            }
    #pragma unroll
    for (int msk = 1; msk <= 8; msk <<= 1)
        #pragma unroll
        for (int m = 0; m < 2; ++m)
            #pragma unroll
            for (int r = 0; r < 4; ++r)
                ssq[m][r] += __shfl_xor(ssq[m][r], msk);

    const float* maskp = maskf + wv * 32;
    f32x4 mk[2];
    mk[0] = *(const f32x4*)&maskp[4 * lq];
    mk[1] = *(const f32x4*)&maskp[16 + 4 * lq];

    float sc[2][4];
    #pragma unroll
    for (int m = 0; m < 2; ++m)
        #pragma unroll
        for (int r = 0; r < 4; ++r)
            // rsqrt(max(ss,1e-24)) == 1/max(sqrt(ss),1e-12)
            sc[m][r] = (mk[m][r] != 0.f) ? rsqrtf(fmaxf(ssq[m][r], 1e-24f)) : 0.f;

    // ---- store 3 copies (quarter-wave 64B segments) ----
    const int osz = nrows * LAT;                 // 64M, fits int
    float* __restrict__ ob = out + (long long)Rw * LAT;
    #pragma unroll
    for (int m = 0; m < 2; ++m)
        #pragma unroll
        for (int r = 0; r < 4; ++r) {
            const int ro = (16 * m + 4 * lq + r) * LAT;
            #pragma unroll
            for (int n = 0; n < 2; ++n) {
                const float vv = er[m][n][r] * sc[m][r];
                const int cc = ro + lr + 16 * n;
                ob[cc]           = vv;
                ob[osz + cc]     = vv;
                ob[2 * osz + cc] = vv;
            }
        }
}

extern "C" void kernel_launch(void* const* d_in, const int* in_sizes, int n_in,
                              void* d_out, int out_size, void* d_ws, size_t ws_size,
                              hipStream_t stream) {
    const float* inp    = (const float*)d_in[0];
    const float* shiftp = (const float*)d_in[1];
    const float* W1     = (const float*)d_in[2];
    const float* b1     = (const float*)d_in[3];
    const float* Wh0    = (const float*)d_in[4];
    const float* bh0    = (const float*)d_in[5];
    const float* Wh1    = (const float*)d_in[6];
    const float* bh1    = (const float*)d_in[7];
    float* out = (float*)d_out;

    const int nrows = in_sizes[0] / FEAT;      // 2,000,000 = 128 * 15625
    const int blocks = nrows / RPB;            // exact

    material_encoder_kernel<<<dim3(blocks), dim3(THREADS), 0, stream>>>(
        inp, shiftp, W1, b1, Wh0, bh0, Wh1, bh1, out, nrows);
}

// Round 8
// 274.358 us; speedup vs baseline: 1.5568x; 1.5326x over previous
//
#include <hip/hip_runtime.h>

#define FEAT 83
#define DIMF 64
#define LAT  32
#define THREADS 256
#define RPB  128            // rows per block: 4 waves x 32 rows

typedef __attribute__((ext_vector_type(8))) short bf16x8;
typedef __attribute__((ext_vector_type(4))) float f32x4;
typedef __attribute__((ext_vector_type(4))) unsigned u32x4;

// d_ws image (shorts): exact LDS layout, built once by prep kernel
//  bt1: [64 h-cols][96 k] (k 83..95 zeroed)   bt2: [32][64]   bt3: [32][32]
#define BT1H 0
#define BT1L 6144
#define BT2H 12288
#define BT2L 14336
#define BT3H 16384
#define BT3L 17408
#define WS_SHORTS 18432     // 36864 B = 9 * 4096

// LDS map (bytes): [0,36864) weight image | [36864,53248) 4x4096B wave scratch
//                  | [53248,53760) row-mask floats
#define SM_SHORTS 26880     // 53760 B -> 3 blocks/CU

__device__ __forceinline__ short f2b(float f) {   // fp32 -> bf16 RNE
    unsigned u = __float_as_uint(f);
    u += 0x7fffu + ((u >> 16) & 1u);
    return (short)(u >> 16);
}
__device__ __forceinline__ float b2f(short h) {   // bf16 -> fp32 exact
    return __uint_as_float(((unsigned)(unsigned short)h) << 16);
}

// ---- K1: one-time weight hi/lo split into d_ws (tiny, off hot path) ----
__global__ void prep_weights(const float* __restrict__ W1,
                             const float* __restrict__ Wh0,
                             const float* __restrict__ Wh1,
                             short* __restrict__ ws)
{
    const int stride = gridDim.x * blockDim.x;
    const int tid = blockIdx.x * blockDim.x + threadIdx.x;
    for (int idx = tid; idx < 64 * 96; idx += stride) {       // W1^T + K-pad
        int c = idx / 96, k = idx - c * 96;
        float w = (k < FEAT) ? W1[k * 64 + c] : 0.f;
        short hi = f2b(w);
        ws[BT1H + idx] = hi;
        ws[BT1L + idx] = f2b(w - b2f(hi));
    }
    for (int idx = tid; idx < 32 * 64; idx += stride) {       // Wh0^T
        int c = idx >> 6, k = idx & 63;
        float w = Wh0[k * 32 + c];
        short hi = f2b(w);
        ws[BT2H + idx] = hi;
        ws[BT2L + idx] = f2b(w - b2f(hi));
    }
    for (int idx = tid; idx < 32 * 32; idx += stride) {       // Wh1^T
        int c = idx >> 5, k = idx & 31;
        float w = Wh1[k * 32 + c];
        short hi = f2b(w);
        ws[BT3H + idx] = hi;
        ws[BT3L + idx] = f2b(w - b2f(hi));
    }
}

// unpack 8 packed (hi<<16|lo) dwords -> two bf16x8 fragments
__device__ __forceinline__ void unpack8(const unsigned* p, bf16x8& hi, bf16x8& lo) {
    union { bf16x8 v; unsigned u[4]; } H, L;
    #pragma unroll
    for (int d = 0; d < 4; ++d) {
        H.u[d] = __builtin_amdgcn_perm(p[2 * d + 1], p[2 * d], 0x07060302u);
        L.u[d] = __builtin_amdgcn_perm(p[2 * d + 1], p[2 * d], 0x05040100u);
    }
    hi = H.v; lo = L.v;
}

__global__ __launch_bounds__(THREADS, 3)
void material_encoder_kernel(const float* __restrict__ inp,
                             const float* __restrict__ shiftp,
                             const short* __restrict__ ws,
                             const float* __restrict__ b1,
                             const float* __restrict__ bh0,
                             const float* __restrict__ bh1,
                             float* __restrict__ out,
                             int nrows)
{
    __shared__ __align__(16) short sm[SM_SHORTS];
    unsigned* scr = (unsigned*)((char*)sm + 36864) + (threadIdx.x >> 6) * 1024;
    float* maskf  = (float*)((char*)sm + 53248);

    const int t    = threadIdx.x;
    const int lane = t & 63;
    const int wv   = t >> 6;
    const int lr   = lane & 15;        // A-row / B-col / C-col index
    const int lq   = (lane >> 4) & 3;  // lane quarter

    // ---- weight image: load early (latency hides under x build), write late ----
    f32x4 wreg[9];
    {
        const f32x4* __restrict__ wsrc = (const f32x4*)ws;
        #pragma unroll
        for (int it = 0; it < 9; ++it) wreg[it] = wsrc[it * THREADS + t];
    }

    // biases per lane (L2-cached)
    float bias1[4], bias2[2], bias3[2];
    #pragma unroll
    for (int n = 0; n < 4; ++n) bias1[n] = b1[lr + 16 * n];
    #pragma unroll
    for (int n = 0; n < 2; ++n) { bias2[n] = bh0[lr + 16 * n]; bias3[n] = bh1[lr + 16 * n]; }
    const float sh = shiftp[0];
    const int Rw = blockIdx.x * RPB + wv * 32;

    // ---- A fragments (x+shift) hi/lo straight from global; nz mask on raw x ----
    // frag layout (16x16x32): row = lr, k = 8*lq + i (+32*s); trunc-hi split
    bf16x8 a1h[2][3], a1l[2][3];
    float nzm[2];
    #pragma unroll
    for (int m = 0; m < 2; ++m) {
        const float* __restrict__ xr = inp + (long long)(Rw + 16 * m + lr) * FEAT;
        float nz = 0.f;
        #pragma unroll
        for (int s = 0; s < 3; ++s) {
            const int k0 = 32 * s + 8 * lq;
            bf16x8 fh, fl;
            #pragma unroll
            for (int i = 0; i < 8; ++i) {
                const int kk = k0 + i;
                float x = 0.f;
                if (kk < FEAT) x = xr[kk];           // predicated; pads -> 0
                nz = fmaxf(nz, fabsf(x));
                const float xs = x + sh;
                const unsigned u = __float_as_uint(xs);
                fh[i] = (short)(u >> 16);            // truncation hi
                fl[i] = f2b(xs - __uint_as_float(u & 0xffff0000u));
            }
            a1h[m][s] = fh;
            a1l[m][s] = fl;
        }
        nzm[m] = nz;
    }
    #pragma unroll
    for (int m = 0; m < 2; ++m) {     // full-row max across the 4 k-quarters
        nzm[m] = fmaxf(nzm[m], __shfl_xor(nzm[m], 16));
        nzm[m] = fmaxf(nzm[m], __shfl_xor(nzm[m], 32));
    }
    if (lq == 0) {
        maskf[wv * 32 + lr]      = nzm[0];
        maskf[wv * 32 + 16 + lr] = nzm[1];
    }

    // ---- write weight image to LDS (linear b128, conflict-free), one barrier ----
    {
        f32x4* wdst = (f32x4*)sm;
        #pragma unroll
        for (int it = 0; it < 9; ++it) wdst[it * THREADS + t] = wreg[it];
    }
    __syncthreads();   // the ONLY barrier

    // ---- layer 1: 2(M) x 4(N) x 3(K) x 3 split-terms ----
    f32x4 acc[2][4];
    #pragma unroll
    for (int m = 0; m < 2; ++m)
        #pragma unroll
        for (int n = 0; n < 4; ++n)
            acc[m][n] = (f32x4){bias1[n], bias1[n], bias1[n], bias1[n]};

    #pragma unroll
    for (int s = 0; s < 3; ++s)
        #pragma unroll
        for (int n = 0; n < 4; ++n) {
            bf16x8 bh = *(const bf16x8*)&sm[BT1H + (lr + 16 * n) * 96 + 32 * s + 8 * lq];
            bf16x8 bl = *(const bf16x8*)&sm[BT1L + (lr + 16 * n) * 96 + 32 * s + 8 * lq];
            #pragma unroll
            for (int m = 0; m < 2; ++m) {
                acc[m][n] = __builtin_amdgcn_mfma_f32_16x16x32_bf16(a1h[m][s], bh, acc[m][n], 0, 0, 0);
                acc[m][n] = __builtin_amdgcn_mfma_f32_16x16x32_bf16(a1l[m][s], bh, acc[m][n], 0, 0, 0);
                acc[m][n] = __builtin_amdgcn_mfma_f32_16x16x32_bf16(a1h[m][s], bl, acc[m][n], 0, 0, 0);
            }
        }

    // ---- layer 2 via per-wave packed scratch, chunked over 32-col halves ----
    f32x4 acc2[2][2];
    #pragma unroll
    for (int m = 0; m < 2; ++m)
        #pragma unroll
        for (int n = 0; n < 2; ++n)
            acc2[m][n] = (f32x4){bias2[n], bias2[n], bias2[n], bias2[n]};

    #pragma unroll
    for (int s = 0; s < 2; ++s) {
        // write chunk s (h-dims 32s..32s+31) as packed hi|lo u32, [32][32]
        #pragma unroll
        for (int m = 0; m < 2; ++m)
            #pragma unroll
            for (int np = 0; np < 2; ++np)
                #pragma unroll
                for (int r = 0; r < 4; ++r) {
                    const float hv = fmaxf(acc[m][2 * s + np][r], 0.f);
                    const unsigned u = __float_as_uint(hv);
                    const unsigned hiu = u & 0xffff0000u;
                    const unsigned lo16 =
                        (unsigned short)f2b(hv - __uint_as_float(hiu));
                    scr[(16 * m + 4 * lq + r) * 32 + lr + 16 * np] = hiu | lo16;
                }
        // read A-frags (same-wave DS ordering; no barrier)
        bf16x8 a2h[2], a2l[2];
        #pragma unroll
        for (int m = 0; m < 2; ++m) {
            unsigned p[8];
            *(u32x4*)&p[0] = *(const u32x4*)&scr[(lr + 16 * m) * 32 + 8 * lq];
            *(u32x4*)&p[4] = *(const u32x4*)&scr[(lr + 16 * m) * 32 + 8 * lq + 4];
            unpack8(p, a2h[m], a2l[m]);
        }
        #pragma unroll
        for (int n = 0; n < 2; ++n) {
            bf16x8 bh = *(const bf16x8*)&sm[BT2H + (lr + 16 * n) * 64 + 32 * s + 8 * lq];
            bf16x8 bl = *(const bf16x8*)&sm[BT2L + (lr + 16 * n) * 64 + 32 * s + 8 * lq];
            #pragma unroll
            for (int m = 0; m < 2; ++m) {
                acc2[m][n] = __builtin_amdgcn_mfma_f32_16x16x32_bf16(a2h[m], bh, acc2[m][n], 0, 0, 0);
                acc2[m][n] = __builtin_amdgcn_mfma_f32_16x16x32_bf16(a2l[m], bh, acc2[m][n], 0, 0, 0);
                acc2[m][n] = __builtin_amdgcn_mfma_f32_16x16x32_bf16(a2h[m], bl, acc2[m][n], 0, 0, 0);
            }
        }
    }

    // ---- layer 3: g through the same scratch (reused, same-wave order) ----
    f32x4 acc3[2][2];
    #pragma unroll
    for (int m = 0; m < 2; ++m)
        #pragma unroll
        for (int n = 0; n < 2; ++n)
            acc3[m][n] = (f32x4){bias3[n], bias3[n], bias3[n], bias3[n]};

    #pragma unroll
    for (int m = 0; m < 2; ++m)
        #pragma unroll
        for (int n = 0; n < 2; ++n)
            #pragma unroll
            for (int r = 0; r < 4; ++r) {
                const float gv = fmaxf(acc2[m][n][r], 0.f);
                const unsigned u = __float_as_uint(gv);
                const unsigned hiu = u & 0xffff0000u;
                const unsigned lo16 =
                    (unsigned short)f2b(gv - __uint_as_float(hiu));
                scr[(16 * m + 4 * lq + r) * 32 + lr + 16 * n] = hiu | lo16;
            }
    {
        bf16x8 a3h[2], a3l[2];
        #pragma unroll
        for (int m = 0; m < 2; ++m) {
            unsigned p[8];
            *(u32x4*)&p[0] = *(const u32x4*)&scr[(lr + 16 * m) * 32 + 8 * lq];
            *(u32x4*)&p[4] = *(const u32x4*)&scr[(lr + 16 * m) * 32 + 8 * lq + 4];
            unpack8(p, a3h[m], a3l[m]);
        }
        #pragma unroll
        for (int n = 0; n < 2; ++n) {
            bf16x8 bh = *(const bf16x8*)&sm[BT3H + (lr + 16 * n) * 32 + 8 * lq];
            bf16x8 bl = *(const bf16x8*)&sm[BT3L + (lr + 16 * n) * 32 + 8 * lq];
            #pragma unroll
            for (int m = 0; m < 2; ++m) {
                acc3[m][n] = __builtin_amdgcn_mfma_f32_16x16x32_bf16(a3h[m], bh, acc3[m][n], 0, 0, 0);
                acc3[m][n] = __builtin_amdgcn_mfma_f32_16x16x32_bf16(a3l[m], bh, acc3[m][n], 0, 0, 0);
                acc3[m][n] = __builtin_amdgcn_mfma_f32_16x16x32_bf16(a3h[m], bl, acc3[m][n], 0, 0, 0);
            }
        }
    }

    // ---- relu + row L2 norm (reduce over cols = over lr lanes) + mask ----
    float er[2][2][4];
    float ssq[2][4];
    #pragma unroll
    for (int m = 0; m < 2; ++m)
        #pragma unroll
        for (int r = 0; r < 4; ++r) ssq[m][r] = 0.f;
    #pragma unroll
    for (int m = 0; m < 2; ++m)
        #pragma unroll
        for (int n = 0; n < 2; ++n)
            #pragma unroll
            for (int r = 0; r < 4; ++r) {
                float e = fmaxf(acc3[m][n][r], 0.f);
                er[m][n][r] = e;
                ssq[m][r] = fmaf(e, e, ssq[m][r]);
            }
    #pragma unroll
    for (int msk = 1; msk <= 8; msk <<= 1)
        #pragma unroll
        for (int m = 0; m < 2; ++m)
            #pragma unroll
            for (int r = 0; r < 4; ++r)
                ssq[m][r] += __shfl_xor(ssq[m][r], msk);

    const float* maskp = maskf + wv * 32;
    f32x4 mk[2];
    mk[0] = *(const f32x4*)&maskp[4 * lq];
    mk[1] = *(const f32x4*)&maskp[16 + 4 * lq];

    float sc[2][4];
    #pragma unroll
    for (int m = 0; m < 2; ++m)
        #pragma unroll
        for (int r = 0; r < 4; ++r)
            // rsqrt(max(ss,1e-24)) == 1/max(sqrt(ss),1e-12)
            sc[m][r] = (mk[m][r] != 0.f) ? rsqrtf(fmaxf(ssq[m][r], 1e-24f)) : 0.f;

    // ---- store 3 copies (quarter-wave 64B segments) ----
    const int osz = nrows * LAT;                 // 64M, fits int
    float* __restrict__ ob = out + (long long)Rw * LAT;
    #pragma unroll
    for (int m = 0; m < 2; ++m)
        #pragma unroll
        for (int r = 0; r < 4; ++r) {
            const int ro = (16 * m + 4 * lq + r) * LAT;
            #pragma unroll
            for (int n = 0; n < 2; ++n) {
                const float vv = er[m][n][r] * sc[m][r];
                const int cc = ro + lr + 16 * n;
                ob[cc]           = vv;
                ob[osz + cc]     = vv;
                ob[2 * osz + cc] = vv;
            }
        }
}

extern "C" void kernel_launch(void* const* d_in, const int* in_sizes, int n_in,
                              void* d_out, int out_size, void* d_ws, size_t ws_size,
                              hipStream_t stream) {
    const float* inp    = (const float*)d_in[0];
    const float* shiftp = (const float*)d_in[1];
    const float* W1     = (const float*)d_in[2];
    const float* b1     = (const float*)d_in[3];
    const float* Wh0    = (const float*)d_in[4];
    const float* bh0    = (const float*)d_in[5];
    const float* Wh1    = (const float*)d_in[6];
    const float* bh1    = (const float*)d_in[7];
    float* out = (float*)d_out;
    short* ws  = (short*)d_ws;

    const int nrows = in_sizes[0] / FEAT;      // 2,000,000 = 128 * 15625
    const int blocks = nrows / RPB;            // exact

    prep_weights<<<dim3(24), dim3(THREADS), 0, stream>>>(W1, Wh0, Wh1, ws);
    material_encoder_kernel<<<dim3(blocks), dim3(THREADS), 0, stream>>>(
        inp, shiftp, ws, b1, bh0, bh1, out, nrows);
}